// Round 3
// baseline (1651.824 us; speedup 1.0000x reference)
//
#include <hip/hip_runtime.h>
#include <math.h>

// Dims (fixed by the problem)
#define HH   50          // hidden
#define GG   150         // 3H
#define XGS  152         // xg row stride (padded)
#define TTT  2048        // T
#define NB   64          // batch B
#define MTOT (TTT*NB)    // 131072 rows per layer
#define D0   128         // layer-0 input dim

// ---------------- Layer-0 input projection: Xg = X0 @ W + bi ----------------
// X0 is time-major view of x[B,T,D]: row m = t*B+b -> x[b,t,:]. 32 rows/block.
__global__ __launch_bounds__(256) void proj0_kernel(
    const float* __restrict__ x,              // [64,2048,128] f32
    const float* __restrict__ W,              // [128,150] f32
    const float* __restrict__ bias,           // [2,150] f32 (bi = bias[0])
    float* __restrict__ xg)                   // [MTOT,XGS] f32
{
    __shared__ float xs[32][D0];              // 16 KB
    const int m0 = blockIdx.x * 32;
    const int t  = m0 >> 6;                   // 32 rows in a tile share t
    const int b0 = m0 & 63;
    for (int i = threadIdx.x; i < 32 * D0; i += 256) {
        int r = i >> 7, k = i & (D0 - 1);
        xs[r][k] = x[((size_t)(b0 + r) * TTT + t) * D0 + k];
    }
    __syncthreads();
    for (int idx = threadIdx.x; idx < 8 * GG; idx += 256) {
        int c = idx % GG, rg = idx / GG;      // col + row-group of 4
        const float* x0 = xs[rg * 4 + 0];
        const float* x1 = xs[rg * 4 + 1];
        const float* x2 = xs[rg * 4 + 2];
        const float* x3 = xs[rg * 4 + 3];
        float a0 = 0.f, a1 = 0.f, a2 = 0.f, a3 = 0.f;
        for (int k = 0; k < D0; ++k) {
            float w = W[k * GG + c];
            a0 += x0[k] * w; a1 += x1[k] * w; a2 += x2[k] * w; a3 += x3[k] * w;
        }
        float bv = bias[c];
        size_t base = (size_t)(m0 + rg * 4) * XGS + c;
        xg[base          ] = a0 + bv;
        xg[base +     XGS] = a1 + bv;
        xg[base + 2 * XGS] = a2 + bv;
        xg[base + 3 * XGS] = a3 + bv;
    }
}

// ---------------- Layers 1..5 input projection (K=50, f32 input) ----------------
__global__ __launch_bounds__(256) void projH_kernel(
    const float* __restrict__ Xin,            // [MTOT,50] f32 time-major
    const float* __restrict__ W,              // [50,150] f32
    const float* __restrict__ bias,           // [2,150] f32
    float* __restrict__ xg)                   // [MTOT,XGS] f32
{
    __shared__ float xs[32 * HH];             // 6.4 KB
    const int m0 = blockIdx.x * 32;
    for (int i = threadIdx.x; i < 32 * HH; i += 256) xs[i] = Xin[(size_t)m0 * HH + i];
    __syncthreads();
    for (int idx = threadIdx.x; idx < 8 * GG; idx += 256) {
        int c = idx % GG, rg = idx / GG;
        const float* x0 = xs + (rg * 4 + 0) * HH;
        const float* x1 = xs + (rg * 4 + 1) * HH;
        const float* x2 = xs + (rg * 4 + 2) * HH;
        const float* x3 = xs + (rg * 4 + 3) * HH;
        float a0 = 0.f, a1 = 0.f, a2 = 0.f, a3 = 0.f;
        for (int k = 0; k < HH; ++k) {
            float w = W[k * GG + c];
            a0 += x0[k] * w; a1 += x1[k] * w; a2 += x2[k] * w; a3 += x3[k] * w;
        }
        float bv = bias[c];
        size_t base = (size_t)(m0 + rg * 4) * XGS + c;
        xg[base          ] = a0 + bv;
        xg[base +     XGS] = a1 + bv;
        xg[base + 2 * XGS] = a2 + bv;
        xg[base + 3 * XGS] = a3 + bv;
    }
}

// ---------------- GRU recurrence (Keras reset_after), 8 rows/block ----------------
// Writes output rows permuted back to time-major: n=j*64+b, tau=j*dn+s.
__global__ __launch_bounds__(256) void gru_kernel(
    const float* __restrict__ xg,             // [dn*Nb, XGS] f32 (includes bi)
    const float* __restrict__ U,              // [50,150] f32
    const float* __restrict__ bias,           // [2,150] f32 (br = bias+150)
    float* __restrict__ Xout,                 // [MTOT,50] f32 time-major
    int dn, int Nbatch)
{
    __shared__ float Us[HH * GG];             // 30 KB
    __shared__ float brs[GG];
    __shared__ float hs[8][HH];
    __shared__ float rec[8][GG];
    const int n0 = blockIdx.x * 8;
    for (int i = threadIdx.x; i < HH * GG; i += 256) Us[i] = U[i];
    for (int i = threadIdx.x; i < GG; i += 256) brs[i] = bias[GG + i];
    for (int i = threadIdx.x; i < 8 * HH; i += 256) hs[i / HH][i % HH] = 0.f;
    __syncthreads();
    for (int s = 0; s < dn; ++s) {
        // rec = h @ U + br   (8 rows x 150 cols, K=50)
        for (int idx = threadIdx.x; idx < 8 * GG; idx += 256) {
            int c = idx % GG, r = idx / GG;
            const float* hr = hs[r];
            float acc = brs[c];
            for (int k = 0; k < HH; ++k) acc += hr[k] * Us[k * GG + c];
            rec[r][c] = acc;
        }
        __syncthreads();
        // gates + state update + permuted store
        for (int idx = threadIdx.x; idx < 8 * HH; idx += 256) {
            int k = idx % HH, r = idx / HH;
            int n = n0 + r;
            size_t grow = ((size_t)s * Nbatch + n) * XGS;
            float xz = xg[grow + k];
            float xr = xg[grow + HH + k];
            float xh = xg[grow + 2 * HH + k];
            float rz = rec[r][k], rr = rec[r][HH + k], rh = rec[r][2 * HH + k];
            float z  = 1.f / (1.f + expf(-(xz + rz)));
            float rg = 1.f / (1.f + expf(-(xr + rr)));
            float hh = tanhf(xh + rg * rh);
            float hp = hs[r][k];
            float hn = z * hp + (1.f - z) * hh;
            int j = n >> 6, bb = n & 63;
            Xout[((size_t)(j * dn + s) * NB + bb) * HH + k] = hn;
            hs[r][k] = hn;
        }
        __syncthreads();
    }
}

// ---------------- Head: h = relu(feats @ W2 + b2) ----------------
// grid (7, 8): x = 256-col chunk, y = 8-row group of batch
__global__ __launch_bounds__(256) void dense2_kernel(
    const float* __restrict__ X,              // [MTOT,50] f32 final layer (time-major)
    const float* __restrict__ W2,             // [1600,1600] f32
    const float* __restrict__ b2,             // [1600] f32
    float* __restrict__ hout)                 // [64,1600] f32
{
    __shared__ float fs[8][1600];             // 51.2 KB
    const int c  = blockIdx.x * 256 + threadIdx.x;
    const int r0 = blockIdx.y * 8;
    for (int i = threadIdx.x; i < 8 * 1600; i += 256) {
        int r = i / 1600, f = i % 1600;
        int j = f / HH, k = f % HH;           // feats[b, j*50+k] = X[2016+j, b, k]
        fs[r][f] = X[((size_t)(TTT - 32 + j) * NB + (r0 + r)) * HH + k];
    }
    __syncthreads();
    if (c < 1600) {
        float a[8] = {0, 0, 0, 0, 0, 0, 0, 0};
        for (int f = 0; f < 1600; ++f) {
            float w = W2[(size_t)f * 1600 + c];
            #pragma unroll
            for (int r = 0; r < 8; ++r) a[r] += fs[r][f] * w;
        }
        float bv = b2[c];
        #pragma unroll
        for (int r = 0; r < 8; ++r) {
            float v = a[r] + bv;
            hout[(size_t)(r0 + r) * 1600 + c] = v > 0.f ? v : 0.f;
        }
    }
}

// ---------------- Classifier + softmax -> f32 out ----------------
__global__ __launch_bounds__(256) void cls_kernel(
    const float* __restrict__ hin,            // [64,1600] f32
    const float* __restrict__ Wc,             // [1600,41] f32
    const float* __restrict__ bc,             // [41] f32
    float* __restrict__ out)                  // [64,41] f32
{
    __shared__ float hrow[1600];
    __shared__ float lg[41];
    __shared__ float red[2];
    const int b = blockIdx.x;
    for (int i = threadIdx.x; i < 1600; i += 256) hrow[i] = hin[(size_t)b * 1600 + i];
    __syncthreads();
    const int t = threadIdx.x;
    if (t < 41) {
        float acc = bc[t];
        for (int f = 0; f < 1600; ++f) acc += hrow[f] * Wc[f * 41 + t];
        lg[t] = acc;
    }
    __syncthreads();
    if (t == 0) {
        float mx = lg[0];
        for (int i = 1; i < 41; ++i) mx = fmaxf(mx, lg[i]);
        red[0] = mx;
    }
    __syncthreads();
    if (t < 41) lg[t] = expf(lg[t] - red[0]);
    __syncthreads();
    if (t == 0) {
        float sm = 0.f;
        for (int i = 0; i < 41; ++i) sm += lg[i];
        red[1] = 1.f / sm;
    }
    __syncthreads();
    if (t < 41) out[b * 41 + t] = lg[t] * red[1];
}

extern "C" void kernel_launch(void* const* d_in, const int* in_sizes, int n_in,
                              void* d_out, int out_size, void* d_ws, size_t ws_size,
                              hipStream_t stream)
{
    const float* x   = (const float*)d_in[0];    // [64,2048,128]
    const float* W0  = (const float*)d_in[1];    // [128,150]
    const float* U0  = (const float*)d_in[2];    // [50,150]
    const float* b0  = (const float*)d_in[3];    // [2,150]
    const float* Ws  = (const float*)d_in[4];    // [5,50,150]
    const float* Us  = (const float*)d_in[5];    // [5,50,150]
    const float* bs  = (const float*)d_in[6];    // [5,2,150]
    const float* W2  = (const float*)d_in[7];    // [1600,1600]
    const float* b2  = (const float*)d_in[8];    // [1600]
    const float* Wc  = (const float*)d_in[9];    // [1600,41]
    const float* bc  = (const float*)d_in[10];   // [41]

    float* xg   = (float*)d_ws;                       // MTOT*XGS f32  (79.7 MB)
    float* Xbuf = xg + (size_t)MTOT * XGS;            // MTOT*50 f32   (26.2 MB)
    float* hbuf = Xbuf + (size_t)MTOT * HH;           // 64*1600 f32

    static const int rates[6] = {32, 64, 128, 256, 512, 1024};

    // layer 0
    proj0_kernel<<<MTOT / 32, 256, 0, stream>>>(x, W0, b0, xg);
    gru_kernel<<<(rates[0] * NB) / 8, 256, 0, stream>>>(xg, U0, b0, Xbuf,
                                                        TTT / rates[0], rates[0] * NB);
    // layers 1..5
    for (int l = 1; l < 6; ++l) {
        const float* Wl = Ws + (size_t)(l - 1) * HH * GG;
        const float* Ul = Us + (size_t)(l - 1) * HH * GG;
        const float* bl = bs + (size_t)(l - 1) * 2 * GG;
        projH_kernel<<<MTOT / 32, 256, 0, stream>>>(Xbuf, Wl, bl, xg);
        int rate = rates[l];
        gru_kernel<<<(rate * NB) / 8, 256, 0, stream>>>(xg, Ul, bl, Xbuf,
                                                        TTT / rate, rate * NB);
    }
    // head
    dense2_kernel<<<dim3(7, 8), 256, 0, stream>>>(Xbuf, W2, b2, hbuf);
    cls_kernel<<<NB, 256, 0, stream>>>(hbuf, Wc, bc, (float*)d_out);
}

// Round 4
// 1530.029 us; speedup vs baseline: 1.0796x; 1.0796x over previous
//
#include <hip/hip_runtime.h>
#include <math.h>

// Dims (fixed by the problem)
#define HH   50          // hidden
#define GG   150         // 3H
#define XGS  152         // xg row stride (padded)
#define TTT  2048        // T
#define NB   64          // batch B
#define MTOT (TTT*NB)    // 131072 rows per layer
#define D0   128         // layer-0 input dim

// ---------------- Layer-0 input projection: Xg = X0 @ W + bi ----------------
__global__ __launch_bounds__(256) void proj0_kernel(
    const float* __restrict__ x,              // [64,2048,128] f32
    const float* __restrict__ W,              // [128,150] f32
    const float* __restrict__ bias,           // [2,150] f32 (bi = bias[0])
    float* __restrict__ xg)                   // [MTOT,XGS] f32
{
    __shared__ float xs[32][D0];              // 16 KB
    const int m0 = blockIdx.x * 32;
    const int t  = m0 >> 6;                   // 32 rows in a tile share t
    const int b0 = m0 & 63;
    for (int i = threadIdx.x; i < 32 * D0; i += 256) {
        int r = i >> 7, k = i & (D0 - 1);
        xs[r][k] = x[((size_t)(b0 + r) * TTT + t) * D0 + k];
    }
    __syncthreads();
    for (int idx = threadIdx.x; idx < 8 * GG; idx += 256) {
        int c = idx % GG, rg = idx / GG;      // col + row-group of 4
        const float* x0 = xs[rg * 4 + 0];
        const float* x1 = xs[rg * 4 + 1];
        const float* x2 = xs[rg * 4 + 2];
        const float* x3 = xs[rg * 4 + 3];
        float a0 = 0.f, a1 = 0.f, a2 = 0.f, a3 = 0.f;
        for (int k = 0; k < D0; ++k) {
            float w = W[k * GG + c];
            a0 += x0[k] * w; a1 += x1[k] * w; a2 += x2[k] * w; a3 += x3[k] * w;
        }
        float bv = bias[c];
        size_t base = (size_t)(m0 + rg * 4) * XGS + c;
        xg[base          ] = a0 + bv;
        xg[base +     XGS] = a1 + bv;
        xg[base + 2 * XGS] = a2 + bv;
        xg[base + 3 * XGS] = a3 + bv;
    }
}

// ---------------- Layers 1..5 input projection (K=50, f32 input) ----------------
__global__ __launch_bounds__(256) void projH_kernel(
    const float* __restrict__ Xin,            // [MTOT,50] f32 time-major
    const float* __restrict__ W,              // [50,150] f32
    const float* __restrict__ bias,           // [2,150] f32
    float* __restrict__ xg)                   // [MTOT,XGS] f32
{
    __shared__ float xs[32 * HH];             // 6.4 KB
    const int m0 = blockIdx.x * 32;
    for (int i = threadIdx.x; i < 32 * HH; i += 256) xs[i] = Xin[(size_t)m0 * HH + i];
    __syncthreads();
    for (int idx = threadIdx.x; idx < 8 * GG; idx += 256) {
        int c = idx % GG, rg = idx / GG;
        const float* x0 = xs + (rg * 4 + 0) * HH;
        const float* x1 = xs + (rg * 4 + 1) * HH;
        const float* x2 = xs + (rg * 4 + 2) * HH;
        const float* x3 = xs + (rg * 4 + 3) * HH;
        float a0 = 0.f, a1 = 0.f, a2 = 0.f, a3 = 0.f;
        for (int k = 0; k < HH; ++k) {
            float w = W[k * GG + c];
            a0 += x0[k] * w; a1 += x1[k] * w; a2 += x2[k] * w; a3 += x3[k] * w;
        }
        float bv = bias[c];
        size_t base = (size_t)(m0 + rg * 4) * XGS + c;
        xg[base          ] = a0 + bv;
        xg[base +     XGS] = a1 + bv;
        xg[base + 2 * XGS] = a2 + bv;
        xg[base + 3 * XGS] = a3 + bv;
    }
}

// ---------------- GRU recurrence, register-blocked rec matmul ----------------
// R rows/block. rec item = (col-group of NC=4*CQ, row-group of 4): per k,
// CQ ds_read_b128 of U + 4 h broadcasts feed 4*NC FMAs. U padded to 152 cols.
// Output written permuted to time-major: n=j*64+b -> tau=j*dn+s.
template<int R, int CQ, int BLOCK, int NS>
__global__ __launch_bounds__(BLOCK) void gru_t(
    const float* __restrict__ xg,             // [dn*Nbatch, XGS] f32 (includes bi)
    const float* __restrict__ U,              // [50,150] f32
    const float* __restrict__ bias,           // [2,150] f32 (br = bias+150)
    float* __restrict__ Xout,                 // [MTOT,50] f32 time-major
    int dn, int Nbatch)
{
    constexpr int NC     = 4 * CQ;            // cols per item
    constexpr int NQ     = 152 / NC;          // col-groups
    constexpr int NITEMS = NQ * (R / 4);      // rec work items
    __shared__ float Us[50 * 152];            // 30.4 KB, padded cols 150..151 = 0
    __shared__ float brs[152];
    __shared__ float rc[R][152];
    __shared__ float hsm[R][HH];
    const int n0  = blockIdx.x * R;
    const int tid = threadIdx.x;

    for (int i = tid; i < 50 * 152; i += BLOCK) {
        int c = i % 152;
        Us[i] = (c < GG) ? U[(i / 152) * GG + c] : 0.f;
    }
    for (int i = tid; i < 152; i += BLOCK) brs[i] = (i < GG) ? bias[GG + i] : 0.f;
    for (int i = tid; i < R * HH; i += BLOCK) hsm[i / HH][i % HH] = 0.f;
    __syncthreads();

    const int q  = tid % NQ;                  // rec item coords (valid if tid < NITEMS)
    const int rg = tid / NQ;
    const int c0 = NC * q;

    for (int s = 0; s < dn; ++s) {
        // ---- prefetch this step's gate inputs (hides global latency under rec) ----
        float pz[NS], pr[NS], pq[NS];
        #pragma unroll
        for (int u = 0; u < NS; ++u) {
            int i = tid + u * BLOCK;
            if (i < R * HH) {
                int k = i % HH, r = i / HH;
                size_t g = ((size_t)s * Nbatch + n0 + r) * XGS + k;
                pz[u] = xg[g];
                pr[u] = xg[g + HH];
                pq[u] = xg[g + 2 * HH];
            }
        }
        // ---- rec = h @ U  (accumulators in registers) ----
        if (tid < NITEMS) {
            float acc[4][NC];
            #pragma unroll
            for (int j = 0; j < 4; ++j)
                #pragma unroll
                for (int c = 0; c < NC; ++c) acc[j][c] = 0.f;
            for (int k = 0; k < HH; ++k) {
                float w[NC];
                *(float4*)&w[0] = *(const float4*)&Us[k * 152 + c0];
                if (CQ == 2) *(float4*)&w[4] = *(const float4*)&Us[k * 152 + c0 + 4];
                float hv[4];
                #pragma unroll
                for (int j = 0; j < 4; ++j) hv[j] = hsm[rg * 4 + j][k];
                #pragma unroll
                for (int j = 0; j < 4; ++j)
                    #pragma unroll
                    for (int c = 0; c < NC; ++c) acc[j][c] += hv[j] * w[c];
            }
            #pragma unroll
            for (int j = 0; j < 4; ++j) {
                *(float4*)&rc[rg * 4 + j][c0] = *(const float4*)&acc[j][0];
                if (CQ == 2) *(float4*)&rc[rg * 4 + j][c0 + 4] = *(const float4*)&acc[j][4];
            }
        }
        __syncthreads();
        // ---- gates + state update + permuted global store ----
        #pragma unroll
        for (int u = 0; u < NS; ++u) {
            int i = tid + u * BLOCK;
            if (i < R * HH) {
                int k = i % HH, r = i / HH;
                float rz = rc[r][k]          + brs[k];
                float rr = rc[r][HH + k]     + brs[HH + k];
                float rh = rc[r][2 * HH + k] + brs[2 * HH + k];
                float z  = 1.f / (1.f + expf(-(pz[u] + rz)));
                float rg_ = 1.f / (1.f + expf(-(pr[u] + rr)));
                float hh = tanhf(pq[u] + rg_ * rh);
                float hn = z * hsm[r][k] + (1.f - z) * hh;
                hsm[r][k] = hn;
                int n = n0 + r;
                int j = n >> 6, bb = n & 63;
                Xout[((size_t)(j * dn + s) * NB + bb) * HH + k] = hn;
            }
        }
        __syncthreads();
    }
}

// ---------------- Head: h = relu(feats @ W2 + b2) ----------------
__global__ __launch_bounds__(256) void dense2_kernel(
    const float* __restrict__ X,              // [MTOT,50] f32 final layer (time-major)
    const float* __restrict__ W2,             // [1600,1600] f32
    const float* __restrict__ b2,             // [1600] f32
    float* __restrict__ hout)                 // [64,1600] f32
{
    __shared__ float fs[8][1600];             // 51.2 KB
    const int c  = blockIdx.x * 256 + threadIdx.x;
    const int r0 = blockIdx.y * 8;
    for (int i = threadIdx.x; i < 8 * 1600; i += 256) {
        int r = i / 1600, f = i % 1600;
        int j = f / HH, k = f % HH;           // feats[b, j*50+k] = X[2016+j, b, k]
        fs[r][f] = X[((size_t)(TTT - 32 + j) * NB + (r0 + r)) * HH + k];
    }
    __syncthreads();
    if (c < 1600) {
        float a[8] = {0, 0, 0, 0, 0, 0, 0, 0};
        for (int f = 0; f < 1600; ++f) {
            float w = W2[(size_t)f * 1600 + c];
            #pragma unroll
            for (int r = 0; r < 8; ++r) a[r] += fs[r][f] * w;
        }
        float bv = b2[c];
        #pragma unroll
        for (int r = 0; r < 8; ++r) {
            float v = a[r] + bv;
            hout[(size_t)(r0 + r) * 1600 + c] = v > 0.f ? v : 0.f;
        }
    }
}

// ---------------- Classifier + softmax -> f32 out ----------------
__global__ __launch_bounds__(256) void cls_kernel(
    const float* __restrict__ hin,            // [64,1600] f32
    const float* __restrict__ Wc,             // [1600,41] f32
    const float* __restrict__ bc,             // [41] f32
    float* __restrict__ out)                  // [64,41] f32
{
    __shared__ float hrow[1600];
    __shared__ float lg[41];
    __shared__ float red[2];
    const int b = blockIdx.x;
    for (int i = threadIdx.x; i < 1600; i += 256) hrow[i] = hin[(size_t)b * 1600 + i];
    __syncthreads();
    const int t = threadIdx.x;
    if (t < 41) {
        float acc = bc[t];
        for (int f = 0; f < 1600; ++f) acc += hrow[f] * Wc[f * 41 + t];
        lg[t] = acc;
    }
    __syncthreads();
    if (t == 0) {
        float mx = lg[0];
        for (int i = 1; i < 41; ++i) mx = fmaxf(mx, lg[i]);
        red[0] = mx;
    }
    __syncthreads();
    if (t < 41) lg[t] = expf(lg[t] - red[0]);
    __syncthreads();
    if (t == 0) {
        float sm = 0.f;
        for (int i = 0; i < 41; ++i) sm += lg[i];
        red[1] = 1.f / sm;
    }
    __syncthreads();
    if (t < 41) out[b * 41 + t] = lg[t] * red[1];
}

extern "C" void kernel_launch(void* const* d_in, const int* in_sizes, int n_in,
                              void* d_out, int out_size, void* d_ws, size_t ws_size,
                              hipStream_t stream)
{
    const float* x   = (const float*)d_in[0];    // [64,2048,128]
    const float* W0  = (const float*)d_in[1];    // [128,150]
    const float* U0  = (const float*)d_in[2];    // [50,150]
    const float* b0  = (const float*)d_in[3];    // [2,150]
    const float* Ws  = (const float*)d_in[4];    // [5,50,150]
    const float* Us  = (const float*)d_in[5];    // [5,50,150]
    const float* bs  = (const float*)d_in[6];    // [5,2,150]
    const float* W2  = (const float*)d_in[7];    // [1600,1600]
    const float* b2  = (const float*)d_in[8];    // [1600]
    const float* Wc  = (const float*)d_in[9];    // [1600,41]
    const float* bc  = (const float*)d_in[10];   // [41]

    float* xg   = (float*)d_ws;                       // MTOT*XGS f32  (79.7 MB)
    float* Xbuf = xg + (size_t)MTOT * XGS;            // MTOT*50 f32   (26.2 MB)
    float* hbuf = Xbuf + (size_t)MTOT * HH;           // 64*1600 f32

    static const int rates[6] = {32, 64, 128, 256, 512, 1024};

    // layer 0: Nbatch=2048, dn=64  -> R=8,  CQ=1, BLOCK=128, NS=4 (256 blocks)
    proj0_kernel<<<MTOT / 32, 256, 0, stream>>>(x, W0, b0, xg);
    gru_t<8, 1, 128, 4><<<rates[0] * NB / 8, 128, 0, stream>>>(
        xg, U0, b0, Xbuf, TTT / rates[0], rates[0] * NB);

    for (int l = 1; l < 6; ++l) {
        const float* Wl = Ws + (size_t)(l - 1) * HH * GG;
        const float* Ul = Us + (size_t)(l - 1) * HH * GG;
        const float* bl = bs + (size_t)(l - 1) * 2 * GG;
        projH_kernel<<<MTOT / 32, 256, 0, stream>>>(Xbuf, Wl, bl, xg);
        int rate = rates[l];
        int Nbatch = rate * NB;
        int dn = TTT / rate;
        if (l == 1) {
            // Nbatch=4096 -> R=16, CQ=2, BLOCK=128, NS=7 (256 blocks)
            gru_t<16, 2, 128, 7><<<Nbatch / 16, 128, 0, stream>>>(
                xg, Ul, bl, Xbuf, dn, Nbatch);
        } else {
            // R=32, CQ=2, BLOCK=192, NS=9 (256..2048 blocks)
            gru_t<32, 2, 192, 9><<<Nbatch / 32, 192, 0, stream>>>(
                xg, Ul, bl, Xbuf, dn, Nbatch);
        }
    }
    // head
    dense2_kernel<<<dim3(7, 8), 256, 0, stream>>>(Xbuf, W2, b2, hbuf);
    cls_kernel<<<NB, 256, 0, stream>>>(hbuf, Wc, bc, (float*)d_out);
}

// Round 5
// 1220.796 us; speedup vs baseline: 1.3531x; 1.2533x over previous
//
#include <hip/hip_runtime.h>
#include <math.h>

// Dims (fixed by the problem)
#define HH   50          // hidden
#define GG   150         // 3H
#define XGS  152         // xg row stride (padded)
#define TTT  2048        // T
#define NB   64          // batch B
#define MTOT (TTT*NB)    // 131072 rows per layer
#define D0   128         // layer-0 input dim

static __device__ __forceinline__ float sigm(float x) {
    return 1.f / (1.f + __expf(-x));
}
static __device__ __forceinline__ float tanh_f(float x) {
    return 1.f - 2.f / (__expf(2.f * x) + 1.f);   // saturates correctly at +/-inf
}

// ---------------- Layer-0 input projection: Xg = X0 @ W + bi ----------------
__global__ __launch_bounds__(256) void proj0_kernel(
    const float* __restrict__ x,              // [64,2048,128] f32
    const float* __restrict__ W,              // [128,150] f32
    const float* __restrict__ bias,           // [2,150] f32 (bi = bias[0])
    float* __restrict__ xg)                   // [MTOT,XGS] f32
{
    __shared__ float xs[32][D0];              // 16 KB
    const int m0 = blockIdx.x * 32;
    const int t  = m0 >> 6;                   // 32 rows in a tile share t
    const int b0 = m0 & 63;
    for (int i = threadIdx.x; i < 32 * D0; i += 256) {
        int r = i >> 7, k = i & (D0 - 1);
        xs[r][k] = x[((size_t)(b0 + r) * TTT + t) * D0 + k];
    }
    __syncthreads();
    for (int idx = threadIdx.x; idx < 8 * GG; idx += 256) {
        int c = idx % GG, rg = idx / GG;      // col + row-group of 4
        const float* x0 = xs[rg * 4 + 0];
        const float* x1 = xs[rg * 4 + 1];
        const float* x2 = xs[rg * 4 + 2];
        const float* x3 = xs[rg * 4 + 3];
        float a0 = 0.f, a1 = 0.f, a2 = 0.f, a3 = 0.f;
        for (int k = 0; k < D0; ++k) {
            float w = W[k * GG + c];
            a0 += x0[k] * w; a1 += x1[k] * w; a2 += x2[k] * w; a3 += x3[k] * w;
        }
        float bv = bias[c];
        size_t base = (size_t)(m0 + rg * 4) * XGS + c;
        xg[base          ] = a0 + bv;
        xg[base +     XGS] = a1 + bv;
        xg[base + 2 * XGS] = a2 + bv;
        xg[base + 3 * XGS] = a3 + bv;
    }
}

// ---------------- Layers 1..5 input projection (K=50, f32 input) ----------------
__global__ __launch_bounds__(256) void projH_kernel(
    const float* __restrict__ Xin,            // [MTOT,50] f32 time-major
    const float* __restrict__ W,              // [50,150] f32
    const float* __restrict__ bias,           // [2,150] f32
    float* __restrict__ xg)                   // [MTOT,XGS] f32
{
    __shared__ float xs[32 * HH];             // 6.4 KB
    const int m0 = blockIdx.x * 32;
    for (int i = threadIdx.x; i < 32 * HH; i += 256) xs[i] = Xin[(size_t)m0 * HH + i];
    __syncthreads();
    for (int idx = threadIdx.x; idx < 8 * GG; idx += 256) {
        int c = idx % GG, rg = idx / GG;
        const float* x0 = xs + (rg * 4 + 0) * HH;
        const float* x1 = xs + (rg * 4 + 1) * HH;
        const float* x2 = xs + (rg * 4 + 2) * HH;
        const float* x3 = xs + (rg * 4 + 3) * HH;
        float a0 = 0.f, a1 = 0.f, a2 = 0.f, a3 = 0.f;
        for (int k = 0; k < HH; ++k) {
            float w = W[k * GG + c];
            a0 += x0[k] * w; a1 += x1[k] * w; a2 += x2[k] * w; a3 += x3[k] * w;
        }
        float bv = bias[c];
        size_t base = (size_t)(m0 + rg * 4) * XGS + c;
        xg[base          ] = a0 + bv;
        xg[base +     XGS] = a1 + bv;
        xg[base + 2 * XGS] = a2 + bv;
        xg[base + 3 * XGS] = a3 + bv;
    }
}

// ---------------- GRU recurrence, barrier-free wave-autonomous ----------------
// WPB waves/block; each wave owns 4 rows for the whole sequence. No
// __syncthreads inside the step loop: hsT/rc slices are per-wave, DS ops of a
// wave complete in order. rec item = 4 rows x 4 cols: per k, 1 ds_read_b128 of
// U + 1 ds_read_b128 of transposed h feed 16 FMAs. br bias lives in registers
// (cols fixed per lane); h_prev lives in gate-lane registers.
// Output written permuted to time-major: n=j*64+b -> tau=j*dn+s.
template<int WPB>
__global__ __launch_bounds__(WPB * 64) void gru_wave(
    const float* __restrict__ xg,             // [dn*Nbatch, XGS] f32 (includes bi)
    const float* __restrict__ U,              // [50,150] f32
    const float* __restrict__ bias,           // [2,150] f32 (br = bias+150)
    float* __restrict__ Xout,                 // [MTOT,50] f32 time-major
    int dn, int Nbatch)
{
    constexpr int R = 4 * WPB;                // rows per block
    __shared__ __align__(16) float Us[HH * XGS];      // 30.4 KB (cols padded to 152)
    __shared__ __align__(16) float brs[XGS];
    __shared__ __align__(16) float hsT[HH][R];        // transposed h, wave w owns cols 4w..4w+3
    __shared__ __align__(16) float rc[R][XGS];        // rec result, wave w owns rows 4w..4w+3

    const int tid  = threadIdx.x;
    const int wav  = tid >> 6;
    const int lane = tid & 63;

    for (int i = tid; i < HH * XGS; i += WPB * 64) {
        int c = i % XGS;
        Us[i] = (c < GG) ? U[(i / XGS) * GG + c] : 0.f;
    }
    for (int i = tid; i < XGS; i += WPB * 64) brs[i] = (i < GG) ? bias[GG + i] : 0.f;
    for (int i = tid; i < HH * R; i += WPB * 64) ((float*)hsT)[i] = 0.f;
    __syncthreads();                          // the only block-wide barrier

    // rec role: lanes 0..37 each own a 4-col group (cg) x this wave's 4 rows
    const int cg = lane;                      // valid if < 38
    float4 brv = make_float4(0.f, 0.f, 0.f, 0.f);
    if (cg < 38) brv = *(const float4*)&brs[cg * 4];

    // gate role: lane = gr*16 + gk handles (row gr, k = gk+16u)
    const int gr = lane >> 4;                 // 0..3 row within wave
    const int gk = lane & 15;
    const int nrow = blockIdx.x * R + wav * 4 + gr;
    const int jj = nrow >> 6, bb = nrow & 63;
    float hprev[4] = {0.f, 0.f, 0.f, 0.f};

    for (int s = 0; s < dn; ++s) {
        // ---- prefetch this step's gate inputs (lands during rec) ----
        float pz[4], pr[4], ph[4];
        {
            const float* g = xg + ((size_t)s * Nbatch + nrow) * XGS;
            #pragma unroll
            for (int u = 0; u < 4; ++u) {
                int k = gk + 16 * u;
                if (k < HH) { pz[u] = g[k]; pr[u] = g[HH + k]; ph[u] = g[2 * HH + k]; }
            }
        }
        // ---- rec = h @ U + br (this wave's 4 rows x 152 cols) ----
        if (cg < 38) {
            float acc[4][4];
            #pragma unroll
            for (int j = 0; j < 4; ++j) {
                acc[j][0] = brv.x; acc[j][1] = brv.y; acc[j][2] = brv.z; acc[j][3] = brv.w;
            }
            #pragma unroll
            for (int k = 0; k < HH; ++k) {
                float4 w  = *(const float4*)&Us[k * XGS + cg * 4];
                float4 hv = *(const float4*)&hsT[k][wav * 4];
                float hj[4] = {hv.x, hv.y, hv.z, hv.w};
                float wc[4] = {w.x, w.y, w.z, w.w};
                #pragma unroll
                for (int j = 0; j < 4; ++j)
                    #pragma unroll
                    for (int c = 0; c < 4; ++c) acc[j][c] += hj[j] * wc[c];
            }
            #pragma unroll
            for (int j = 0; j < 4; ++j)
                *(float4*)&rc[wav * 4 + j][cg * 4] = *(const float4*)&acc[j][0];
        }
        // ---- gates + state update + permuted global store ----
        const float* rcrow = rc[wav * 4 + gr];
        #pragma unroll
        for (int u = 0; u < 4; ++u) {
            int k = gk + 16 * u;
            if (k < HH) {
                float rcz = rcrow[k];
                float rcr = rcrow[HH + k];
                float rch = rcrow[2 * HH + k];
                float z  = sigm(pz[u] + rcz);
                float rr = sigm(pr[u] + rcr);
                float hh = tanh_f(ph[u] + rr * rch);
                float hn = z * hprev[u] + (1.f - z) * hh;
                hprev[u] = hn;
                hsT[k][wav * 4 + gr] = hn;
                Xout[((size_t)(jj * dn + s) * NB + bb) * HH + k] = hn;
            }
        }
    }
}

// ---------------- Head: h = relu(feats @ W2 + b2) ----------------
__global__ __launch_bounds__(256) void dense2_kernel(
    const float* __restrict__ X,              // [MTOT,50] f32 final layer (time-major)
    const float* __restrict__ W2,             // [1600,1600] f32
    const float* __restrict__ b2,             // [1600] f32
    float* __restrict__ hout)                 // [64,1600] f32
{
    __shared__ float fs[8][1600];             // 51.2 KB
    const int c  = blockIdx.x * 256 + threadIdx.x;
    const int r0 = blockIdx.y * 8;
    for (int i = threadIdx.x; i < 8 * 1600; i += 256) {
        int r = i / 1600, f = i % 1600;
        int j = f / HH, k = f % HH;           // feats[b, j*50+k] = X[2016+j, b, k]
        fs[r][f] = X[((size_t)(TTT - 32 + j) * NB + (r0 + r)) * HH + k];
    }
    __syncthreads();
    if (c < 1600) {
        float a[8] = {0, 0, 0, 0, 0, 0, 0, 0};
        for (int f = 0; f < 1600; ++f) {
            float w = W2[(size_t)f * 1600 + c];
            #pragma unroll
            for (int r = 0; r < 8; ++r) a[r] += fs[r][f] * w;
        }
        float bv = b2[c];
        #pragma unroll
        for (int r = 0; r < 8; ++r) {
            float v = a[r] + bv;
            hout[(size_t)(r0 + r) * 1600 + c] = v > 0.f ? v : 0.f;
        }
    }
}

// ---------------- Classifier + softmax -> f32 out ----------------
__global__ __launch_bounds__(256) void cls_kernel(
    const float* __restrict__ hin,            // [64,1600] f32
    const float* __restrict__ Wc,             // [1600,41] f32
    const float* __restrict__ bc,             // [41] f32
    float* __restrict__ out)                  // [64,41] f32
{
    __shared__ float hrow[1600];
    __shared__ float lg[41];
    __shared__ float red[2];
    const int b = blockIdx.x;
    for (int i = threadIdx.x; i < 1600; i += 256) hrow[i] = hin[(size_t)b * 1600 + i];
    __syncthreads();
    const int t = threadIdx.x;
    if (t < 41) {
        float acc = bc[t];
        for (int f = 0; f < 1600; ++f) acc += hrow[f] * Wc[f * 41 + t];
        lg[t] = acc;
    }
    __syncthreads();
    if (t == 0) {
        float mx = lg[0];
        for (int i = 1; i < 41; ++i) mx = fmaxf(mx, lg[i]);
        red[0] = mx;
    }
    __syncthreads();
    if (t < 41) lg[t] = expf(lg[t] - red[0]);
    __syncthreads();
    if (t == 0) {
        float sm = 0.f;
        for (int i = 0; i < 41; ++i) sm += lg[i];
        red[1] = 1.f / sm;
    }
    __syncthreads();
    if (t < 41) out[b * 41 + t] = lg[t] * red[1];
}

extern "C" void kernel_launch(void* const* d_in, const int* in_sizes, int n_in,
                              void* d_out, int out_size, void* d_ws, size_t ws_size,
                              hipStream_t stream)
{
    const float* x   = (const float*)d_in[0];    // [64,2048,128]
    const float* W0  = (const float*)d_in[1];    // [128,150]
    const float* U0  = (const float*)d_in[2];    // [50,150]
    const float* b0  = (const float*)d_in[3];    // [2,150]
    const float* Ws  = (const float*)d_in[4];    // [5,50,150]
    const float* Us  = (const float*)d_in[5];    // [5,50,150]
    const float* bs  = (const float*)d_in[6];    // [5,2,150]
    const float* W2  = (const float*)d_in[7];    // [1600,1600]
    const float* b2  = (const float*)d_in[8];    // [1600]
    const float* Wc  = (const float*)d_in[9];    // [1600,41]
    const float* bc  = (const float*)d_in[10];   // [41]

    float* xg   = (float*)d_ws;                       // MTOT*XGS f32  (79.7 MB)
    float* Xbuf = xg + (size_t)MTOT * XGS;            // MTOT*50 f32   (26.2 MB)
    float* hbuf = Xbuf + (size_t)MTOT * HH;           // 64*1600 f32

    static const int rates[6] = {32, 64, 128, 256, 512, 1024};

    // layer 0: Nbatch=2048 -> 2-wave blocks (R=8), 256 blocks fill 256 CUs
    proj0_kernel<<<MTOT / 32, 256, 0, stream>>>(x, W0, b0, xg);
    gru_wave<2><<<rates[0] * NB / 8, 128, 0, stream>>>(
        xg, U0, b0, Xbuf, TTT / rates[0], rates[0] * NB);

    for (int l = 1; l < 6; ++l) {
        const float* Wl = Ws + (size_t)(l - 1) * HH * GG;
        const float* Ul = Us + (size_t)(l - 1) * HH * GG;
        const float* bl = bs + (size_t)(l - 1) * 2 * GG;
        projH_kernel<<<MTOT / 32, 256, 0, stream>>>(Xbuf, Wl, bl, xg);
        int rate = rates[l];
        int Nbatch = rate * NB;
        int dn = TTT / rate;
        // 4-wave blocks (R=16): 256..4096 blocks, ~3 blocks/CU occupancy
        gru_wave<4><<<Nbatch / 16, 256, 0, stream>>>(xg, Ul, bl, Xbuf, dn, Nbatch);
    }
    // head
    dense2_kernel<<<dim3(7, 8), 256, 0, stream>>>(Xbuf, W2, b2, hbuf);
    cls_kernel<<<NB, 256, 0, stream>>>(hbuf, Wc, bc, (float*)d_out);
}